// Round 2
// baseline (566.558 us; speedup 1.0000x reference)
//
#include <hip/hip_runtime.h>

// LatentPyramid: quant-noise + transpose grids to [H,W,C] in ws, then
// counting-sort points by 16x16-texel tile for cache locality, then fused
// per-point gather (4-corner concat hi-res, bilinear-zeropad lo-res).
// Output [N, 68] fp32, row n belongs to point n regardless of sort order.

#define QSTEP 0.0625f  // 1/16

constexpr int N_PTS = 2097152;
constexpr int C0 = 12, RES0 = 1024;
constexpr int C1 = 20, RES1 = 512;
constexpr int OUT_C = 4 * C0 + C1;  // 68

constexpr int TILE_SHIFT = 4;                 // 16-texel tiles on hi-res grid
constexpr int TILES_X = RES0 >> TILE_SHIFT;   // 64
constexpr int NBUCKETS = TILES_X * TILES_X;   // 4096
constexpr int SCAN_THREADS = 256;
constexpr int CHUNK = NBUCKETS / SCAN_THREADS;  // 16

// ---------------- pre-pass: fuse noise, transpose [C,H,W] -> [H,W,C] ------

__global__ void __launch_bounds__(256)
prep0(const float* __restrict__ g, const float* __restrict__ nz,
      float* __restrict__ ws) {
    int idx = blockIdx.x * blockDim.x + threadIdx.x;
    const int HW = RES0 * RES0;
    float v[C0];
#pragma unroll
    for (int c = 0; c < C0; ++c)
        v[c] = g[(size_t)c * HW + idx] + (nz[(size_t)c * HW + idx] - 0.5f) * QSTEP;
    float4* dst = (float4*)(ws + (size_t)idx * C0);
    dst[0] = make_float4(v[0], v[1], v[2], v[3]);
    dst[1] = make_float4(v[4], v[5], v[6], v[7]);
    dst[2] = make_float4(v[8], v[9], v[10], v[11]);
}

__global__ void __launch_bounds__(256)
prep1(const float* __restrict__ g, const float* __restrict__ nz,
      float* __restrict__ ws) {
    int idx = blockIdx.x * blockDim.x + threadIdx.x;
    const int HW = RES1 * RES1;
    float v[C1];
#pragma unroll
    for (int c = 0; c < C1; ++c)
        v[c] = g[(size_t)c * HW + idx] + (nz[(size_t)c * HW + idx] - 0.5f) * QSTEP;
    float4* dst = (float4*)(ws + (size_t)idx * C1);
#pragma unroll
    for (int i = 0; i < 5; ++i)
        dst[i] = make_float4(v[4 * i], v[4 * i + 1], v[4 * i + 2], v[4 * i + 3]);
}

// ---------------- counting sort by hi-res tile ----------------------------

__device__ __forceinline__ int bucket_of(float2 p) {
    float px = p.x * (float)RES0 - 0.5f;
    float py = p.y * (float)RES0 - 0.5f;
    int x0 = min(max((int)floorf(px), 0), RES0 - 2);
    int y0 = min(max((int)floorf(py), 0), RES0 - 2);
    return (y0 >> TILE_SHIFT) * TILES_X + (x0 >> TILE_SHIFT);
}

__global__ void __launch_bounds__(256)
zero_counts(unsigned int* __restrict__ cnt) {
    int i = blockIdx.x * blockDim.x + threadIdx.x;
    if (i < NBUCKETS) cnt[i] = 0u;
}

__global__ void __launch_bounds__(256)
hist_kernel(const float2* __restrict__ uv, unsigned int* __restrict__ cnt) {
    __shared__ unsigned int h[NBUCKETS];
    for (int i = threadIdx.x; i < NBUCKETS; i += blockDim.x) h[i] = 0u;
    __syncthreads();
    for (int n = blockIdx.x * blockDim.x + threadIdx.x; n < N_PTS;
         n += gridDim.x * blockDim.x)
        atomicAdd(&h[bucket_of(uv[n])], 1u);
    __syncthreads();
    for (int i = threadIdx.x; i < NBUCKETS; i += blockDim.x) {
        unsigned int v = h[i];
        if (v) atomicAdd(&cnt[i], v);
    }
}

// one block: exclusive scan of cnt[NBUCKETS] -> cursor[NBUCKETS]
__global__ void __launch_bounds__(SCAN_THREADS)
scan_kernel(const unsigned int* __restrict__ cnt,
            unsigned int* __restrict__ cursor) {
    __shared__ unsigned int a[SCAN_THREADS];
    int t = threadIdx.x;
    unsigned int local[CHUNK];
    unsigned int s = 0;
#pragma unroll
    for (int i = 0; i < CHUNK; ++i) {
        local[i] = s;                 // exclusive prefix within chunk
        s += cnt[t * CHUNK + i];
    }
    a[t] = s;
    __syncthreads();
    for (int d = 1; d < SCAN_THREADS; d <<= 1) {
        unsigned int v = (t >= d) ? a[t - d] : 0u;
        __syncthreads();
        a[t] += v;
        __syncthreads();
    }
    unsigned int base = a[t] - s;     // exclusive across chunks
#pragma unroll
    for (int i = 0; i < CHUNK; ++i)
        cursor[t * CHUNK + i] = base + local[i];
}

__global__ void __launch_bounds__(256)
scatter_kernel(const float2* __restrict__ uv, unsigned int* __restrict__ cursor,
               float2* __restrict__ suv, int* __restrict__ sidx) {
    int n = blockIdx.x * blockDim.x + threadIdx.x;
    if (n >= N_PTS) return;
    float2 p = uv[n];
    unsigned int pos = atomicAdd(&cursor[bucket_of(p)], 1u);
    suv[pos] = p;
    sidx[pos] = n;
}

// ---------------- main gather (sorted order) ------------------------------

__device__ __forceinline__ void gather_body(float2 p, int n,
                                            const float* __restrict__ ws0,
                                            const float* __restrict__ ws1,
                                            float* __restrict__ out) {
    float4* o = (float4*)(out + (size_t)n * OUT_C);

    // ---- high-res: 4-corner raw gather (clamped), 12 ch each ----
    {
        float px = p.x * (float)RES0 - 0.5f;
        float py = p.y * (float)RES0 - 0.5f;
        int x0 = min(max((int)floorf(px), 0), RES0 - 2);
        int y0 = min(max((int)floorf(py), 0), RES0 - 2);
        const float4* t00 = (const float4*)(ws0 + ((size_t)y0 * RES0 + x0) * C0);
        const float4* t10 = (const float4*)(ws0 + ((size_t)(y0 + 1) * RES0 + x0) * C0);
        o[0] = t00[0]; o[1] = t00[1]; o[2] = t00[2];
        o[3] = t00[3]; o[4] = t00[4]; o[5] = t00[5];
        o[6] = t10[0]; o[7] = t10[1]; o[8] = t10[2];
        o[9] = t10[3]; o[10] = t10[4]; o[11] = t10[5];
    }

    // ---- low-res: bilinear with zero padding, 20 ch ----
    {
        float qx = p.x * (float)RES1 - 0.5f;
        float qy = p.y * (float)RES1 - 0.5f;
        float fx = floorf(qx), fy = floorf(qy);
        float wx = qx - fx, wy = qy - fy;
        int ix0 = (int)fx, iy0 = (int)fy;

        float acc[C1];
#pragma unroll
        for (int c = 0; c < C1; ++c) acc[c] = 0.f;

        auto tap = [&](int iy, int ix, float w) {
            if (ix < 0 || ix >= RES1 || iy < 0 || iy >= RES1) return;
            const float4* t = (const float4*)(ws1 + ((size_t)iy * RES1 + ix) * C1);
#pragma unroll
            for (int i = 0; i < 5; ++i) {
                float4 v = t[i];
                acc[4 * i + 0] += w * v.x;
                acc[4 * i + 1] += w * v.y;
                acc[4 * i + 2] += w * v.z;
                acc[4 * i + 3] += w * v.w;
            }
        };
        tap(iy0,     ix0,     (1.f - wy) * (1.f - wx));
        tap(iy0,     ix0 + 1, (1.f - wy) * wx);
        tap(iy0 + 1, ix0,     wy * (1.f - wx));
        tap(iy0 + 1, ix0 + 1, wy * wx);

#pragma unroll
        for (int i = 0; i < 5; ++i)
            o[12 + i] = make_float4(acc[4 * i], acc[4 * i + 1],
                                    acc[4 * i + 2], acc[4 * i + 3]);
    }
}

__global__ void __launch_bounds__(256)
gather_sorted(const float2* __restrict__ suv, const int* __restrict__ sidx,
              const float* __restrict__ ws0, const float* __restrict__ ws1,
              float* __restrict__ out) {
    int i = blockIdx.x * blockDim.x + threadIdx.x;  // grid sized exactly
    float2 p = suv[i];
    int n = sidx[i];
    gather_body(p, n, ws0, ws1, out);
}

__global__ void __launch_bounds__(256)
gather_fast(const float* __restrict__ uv, const float* __restrict__ ws0,
            const float* __restrict__ ws1, float* __restrict__ out) {
    int n = blockIdx.x * blockDim.x + threadIdx.x;
    if (n >= N_PTS) return;
    float2 p = ((const float2*)uv)[n];
    gather_body(p, n, ws0, ws1, out);
}

// ---------------- fallback: direct gather from [C,H,W] (tiny ws) ---------

__global__ void __launch_bounds__(256)
gather_direct(const float* __restrict__ uv, const float* __restrict__ g0,
              const float* __restrict__ n0, const float* __restrict__ g1,
              const float* __restrict__ n1, float* __restrict__ out) {
    int n = blockIdx.x * blockDim.x + threadIdx.x;
    if (n >= N_PTS) return;
    float2 p = ((const float2*)uv)[n];
    float* o = out + (size_t)n * OUT_C;

    {
        const int HW = RES0 * RES0;
        float px = p.x * (float)RES0 - 0.5f;
        float py = p.y * (float)RES0 - 0.5f;
        int x0 = min(max((int)floorf(px), 0), RES0 - 2);
        int y0 = min(max((int)floorf(py), 0), RES0 - 2);
        int base[4] = {y0 * RES0 + x0, y0 * RES0 + x0 + 1,
                       (y0 + 1) * RES0 + x0, (y0 + 1) * RES0 + x0 + 1};
#pragma unroll
        for (int t = 0; t < 4; ++t)
#pragma unroll
            for (int c = 0; c < C0; ++c) {
                size_t off = (size_t)c * HW + base[t];
                o[t * C0 + c] = g0[off] + (n0[off] - 0.5f) * QSTEP;
            }
    }
    {
        const int HW = RES1 * RES1;
        float qx = p.x * (float)RES1 - 0.5f;
        float qy = p.y * (float)RES1 - 0.5f;
        float fx = floorf(qx), fy = floorf(qy);
        float wx = qx - fx, wy = qy - fy;
        int ix0 = (int)fx, iy0 = (int)fy;
        float acc[C1];
#pragma unroll
        for (int c = 0; c < C1; ++c) acc[c] = 0.f;
        int ixs[4] = {ix0, ix0 + 1, ix0, ix0 + 1};
        int iys[4] = {iy0, iy0, iy0 + 1, iy0 + 1};
        float w4[4] = {(1.f - wy) * (1.f - wx), (1.f - wy) * wx,
                       wy * (1.f - wx), wy * wx};
#pragma unroll
        for (int t = 0; t < 4; ++t) {
            int ix = ixs[t], iy = iys[t];
            if (ix < 0 || ix >= RES1 || iy < 0 || iy >= RES1) continue;
            float w = w4[t];
#pragma unroll
            for (int c = 0; c < C1; ++c) {
                size_t off = (size_t)c * HW + iy * RES1 + ix;
                acc[c] += w * (g1[off] + (n1[off] - 0.5f) * QSTEP);
            }
        }
#pragma unroll
        for (int c = 0; c < C1; ++c) o[4 * C0 + c] = acc[c];
    }
}

extern "C" void kernel_launch(void* const* d_in, const int* in_sizes, int n_in,
                              void* d_out, int out_size, void* d_ws, size_t ws_size,
                              hipStream_t stream) {
    const float* uv = (const float*)d_in[0];
    const float* g0 = (const float*)d_in[1];
    const float* g1 = (const float*)d_in[2];
    const float* n0 = (const float*)d_in[3];
    const float* n1 = (const float*)d_in[4];
    float* out = (float*)d_out;

    const size_t ws0_elems = (size_t)RES0 * RES0 * C0;   // 12 M floats (48 MB)
    const size_t ws1_elems = (size_t)RES1 * RES1 * C1;   //  5 M floats (20 MB)
    const size_t suv_elems = (size_t)N_PTS * 2;          //  4 M floats (16 MB)
    const size_t sidx_elems = (size_t)N_PTS;             //  2 M ints   ( 8 MB)
    const size_t need_mid = (ws0_elems + ws1_elems) * sizeof(float);
    const size_t need_full = need_mid +
        (suv_elems + sidx_elems + 2 * NBUCKETS) * sizeof(float);

    if (ws_size >= need_full) {
        float* ws0 = (float*)d_ws;
        float* ws1 = ws0 + ws0_elems;
        float2* suv = (float2*)(ws1 + ws1_elems);
        int* sidx = (int*)((float*)suv + suv_elems);
        unsigned int* cnt = (unsigned int*)(sidx + sidx_elems);
        unsigned int* cursor = cnt + NBUCKETS;

        prep0<<<RES0 * RES0 / 256, 256, 0, stream>>>(g0, n0, ws0);
        prep1<<<RES1 * RES1 / 256, 256, 0, stream>>>(g1, n1, ws1);
        zero_counts<<<(NBUCKETS + 255) / 256, 256, 0, stream>>>(cnt);
        hist_kernel<<<1024, 256, 0, stream>>>((const float2*)uv, cnt);
        scan_kernel<<<1, SCAN_THREADS, 0, stream>>>(cnt, cursor);
        scatter_kernel<<<N_PTS / 256, 256, 0, stream>>>((const float2*)uv,
                                                        cursor, suv, sidx);
        gather_sorted<<<N_PTS / 256, 256, 0, stream>>>(suv, sidx, ws0, ws1, out);
    } else if (ws_size >= need_mid) {
        float* ws0 = (float*)d_ws;
        float* ws1 = ws0 + ws0_elems;
        prep0<<<RES0 * RES0 / 256, 256, 0, stream>>>(g0, n0, ws0);
        prep1<<<RES1 * RES1 / 256, 256, 0, stream>>>(g1, n1, ws1);
        gather_fast<<<N_PTS / 256, 256, 0, stream>>>(uv, ws0, ws1, out);
    } else {
        gather_direct<<<N_PTS / 256, 256, 0, stream>>>(uv, g0, n0, g1, n1, out);
    }
}